// Round 1
// baseline (292.581 us; speedup 1.0000x reference)
//
#include <hip/hip_runtime.h>

// GND_61873298866219 — graph attention distance kernel
// Outputs (concat): attentions [E,4] floats, then f_src [E,4,16] floats.

static __device__ __forceinline__ unsigned fmap_ord(float x) {
    // order-preserving float -> uint map (for atomicMin)
    unsigned u = __float_as_uint(x);
    return (u >> 31) ? ~u : (u | 0x80000000u);
}

__global__ __launch_bounds__(256) void gnd_pass1(
    const float4* __restrict__ nodes4,     // [N*16] float4 (N nodes x 64 floats)
    const int* __restrict__ trgA,          // [E]
    const int* __restrict__ srcA,          // [E]
    const float4* __restrict__ w_edge4,    // [16]
    const float4* __restrict__ w_dist4,    // [16]
    float4* __restrict__ out_fsrc4,        // [E*16]
    float* __restrict__ ed,                // [E*4]
    double* __restrict__ gsum,             // [4]
    unsigned* __restrict__ gminu,          // [4]
    int E)
{
    const int lane = threadIdx.x & 63;
    const int q = lane & 15;               // float4 index within node (0..15)
    const int h = (lane >> 2) & 3;         // head for this float4
    const float4 wE = w_edge4[q];
    const float4 wD = w_dist4[q];

    double sumAcc = 0.0;
    float  minAcc = 3.4e38f;

    int gid = blockIdx.x * blockDim.x + threadIdx.x;
    int stride = gridDim.x * blockDim.x;   // multiple of 16
    int total = E * 16;
    for (int i = gid; i < total; i += stride) {
        int e = i >> 4;                    // (i & 15) == q by construction
        int t = trgA[e];
        int s = srcA[e];
        float4 fs = nodes4[s * 16 + q];
        float4 ft = nodes4[t * 16 + q];
        out_fsrc4[e * 16 + q] = fs;
        float ax = (ft.x - fs.x) * wE.x;
        float ay = (ft.y - fs.y) * wE.y;
        float az = (ft.z - fs.z) * wE.z;
        float aw = (ft.w - fs.w) * wE.w;
        float v = ax * ax * wD.x + ay * ay * wD.y + az * az * wD.z + aw * aw * wD.w;
        // reduce the 4 lanes of one head (adjacent lanes)
        v += __shfl_xor(v, 1);
        v += __shfl_xor(v, 2);
        if ((lane & 3) == 0) {
            ed[e * 4 + h] = v;
            sumAcc += (double)v;
            minAcc = fminf(minAcc, v);
        }
    }
    // wave-level: combine the 4 contributing 16-lane groups (same h at lane^16, lane^32)
    sumAcc += __shfl_xor(sumAcc, 16);
    sumAcc += __shfl_xor(sumAcc, 32);
    minAcc = fminf(minAcc, __shfl_xor(minAcc, 16));
    minAcc = fminf(minAcc, __shfl_xor(minAcc, 32));

    __shared__ double sSum[4][4];  // [wave][head]
    __shared__ float  sMin[4][4];
    int wv = threadIdx.x >> 6;
    if (lane < 16 && (lane & 3) == 0) {
        sSum[wv][h] = sumAcc;
        sMin[wv][h] = minAcc;
    }
    __syncthreads();
    if (threadIdx.x < 4) {
        int hh = threadIdx.x;
        double s = sSum[0][hh] + sSum[1][hh] + sSum[2][hh] + sSum[3][hh];
        float  m = fminf(fminf(sMin[0][hh], sMin[1][hh]),
                         fminf(sMin[2][hh], sMin[3][hh]));
        atomicAdd(&gsum[hh], s);
        atomicMin(&gminu[hh], fmap_ord(m));
    }
}

__global__ void gnd_finalize(const double* __restrict__ gsum,
                             const unsigned* __restrict__ gminu,
                             float* __restrict__ consts, int E)
{
    if (threadIdx.x == 0 && blockIdx.x == 0) {
        float smax = -3.4e38f;
        for (int hh = 0; hh < 4; ++hh) {
            float mean = (float)(gsum[hh] / (double)E);
            unsigned m = gminu[hh];
            unsigned bits = (m >> 31) ? (m ^ 0x80000000u) : ~m;
            float mn = __uint_as_float(bits);
            float x = mn + mean;
            float lr = (x >= 0.f) ? x : 0.2f * x;
            smax = fmaxf(smax, -lr);
            consts[hh] = mean;
        }
        consts[4] = smax;
    }
}

static __device__ __forceinline__ float head_mean(float m0, float m1, float m2, float m3, int hh) {
    float a = (hh & 1) ? m1 : m0;
    float b = (hh & 1) ? m3 : m2;
    return (hh & 2) ? b : a;
}

__global__ __launch_bounds__(256) void gnd_pass2(
    const float* __restrict__ ed,
    const int* __restrict__ trgA,
    const float* __restrict__ consts,
    float* __restrict__ denom,             // [N*4], pre-zeroed
    int total)                             // E*4
{
    const float m0 = consts[0], m1 = consts[1], m2 = consts[2], m3 = consts[3];
    const float smax = consts[4];
    int gid = blockIdx.x * blockDim.x + threadIdx.x;
    int stride = gridDim.x * blockDim.x;
    for (int i = gid; i < total; i += stride) {
        int e = i >> 2, hh = i & 3;
        float x = ed[i] + head_mean(m0, m1, m2, m3, hh);
        float lr = (x >= 0.f) ? x : 0.2f * x;
        float ex = expf(-lr - smax);
        atomicAdd(&denom[trgA[e] * 4 + hh], ex);
    }
}

__global__ __launch_bounds__(256) void gnd_pass3(
    const float* __restrict__ ed,
    const int* __restrict__ trgA,
    const float* __restrict__ consts,
    const float* __restrict__ denom,
    float* __restrict__ attOut,            // [E*4]
    int total)
{
    const float m0 = consts[0], m1 = consts[1], m2 = consts[2], m3 = consts[3];
    const float smax = consts[4];
    int gid = blockIdx.x * blockDim.x + threadIdx.x;
    int stride = gridDim.x * blockDim.x;
    for (int i = gid; i < total; i += stride) {
        int e = i >> 2, hh = i & 3;
        float x = ed[i] + head_mean(m0, m1, m2, m3, hh);
        float lr = (x >= 0.f) ? x : 0.2f * x;
        float ex = expf(-lr - smax);           // identical recompute to pass2
        float den = denom[trgA[e] * 4 + hh];
        attOut[i] = ex / (den + 1e-16f);
    }
}

extern "C" void kernel_launch(void* const* d_in, const int* in_sizes, int n_in,
                              void* d_out, int out_size, void* d_ws, size_t ws_size,
                              hipStream_t stream)
{
    const float* nodes  = (const float*)d_in[0];   // [N,4,16]
    const int*   ei     = (const int*)d_in[1];     // [2,E]
    const float* w_edge = (const float*)d_in[2];   // [1,4,16]
    const float* w_dist = (const float*)d_in[3];   // [1,4,16]

    const int N = in_sizes[0] / 64;
    const int E = in_sizes[1] / 2;
    const int* trgA = ei;          // edge_index[0]
    const int* srcA = ei + E;      // edge_index[1]

    float*  out_att   = (float*)d_out;                               // [E*4]
    float4* out_fsrc4 = (float4*)((float*)d_out + (size_t)E * 4);    // [E*16] float4

    // workspace layout
    float*    ed    = (float*)d_ws;                        // E*4 floats
    float*    denom = ed + (size_t)E * 4;                  // N*4 floats
    double*   gsum  = (double*)(denom + (size_t)N * 4);    // 4 doubles (8B aligned)
    unsigned* gminu = (unsigned*)(gsum + 4);               // 4 uints
    float*    consts = (float*)(gminu + 4);                // mean[4], smax

    // zero denom + gsum; init gminu to 0xFFFFFFFF (max for ordered-uint min)
    hipMemsetAsync(denom, 0, (size_t)N * 4 * sizeof(float) + 4 * sizeof(double), stream);
    hipMemsetAsync(gminu, 0xFF, 4 * sizeof(unsigned), stream);

    gnd_pass1<<<2048, 256, 0, stream>>>((const float4*)nodes, trgA, srcA,
                                        (const float4*)w_edge, (const float4*)w_dist,
                                        out_fsrc4, ed, gsum, gminu, E);
    gnd_finalize<<<1, 64, 0, stream>>>(gsum, gminu, consts, E);

    const int total = E * 4;
    gnd_pass2<<<2048, 256, 0, stream>>>(ed, trgA, consts, denom, total);
    gnd_pass3<<<2048, 256, 0, stream>>>(ed, trgA, consts, denom, out_att, total);
}